// Round 2
// baseline (167.337 us; speedup 1.0000x reference)
//
#include <hip/hip_runtime.h>
#include <hip/hip_bf16.h>
#include <hip/hip_cooperative_groups.h>

namespace cg = cooperative_groups;

// NT-Xent loss, N=4096, Z=128, T=0.5.
//
// Round 4: scratch matrix in MFMA-FRAGMENT ORDER -> coalesced dwordx4 frag loads.
// Round 7: full matrix, 64-row waves, reg-double-buffered B: k_simsum ~10 us.
// Round 8: upper-triangle symmetry (row path + mirrored col path), 4224 units
//          strip-partitioned over exactly 512 blocks: k_simsum ~6-7 us.
//          Total only moved 85.7->82.1 us => kernels are ~11-14 us and the
//          window is dominated by the 42 us harness poison-fill plus ~25-29 us
//          of inter-dispatch gaps across 3 launches.
// Round 9: ONE cooperative dispatch. normalize -> grid.sync -> triangle simsum
//          -> last-block ticket does the finish. Saves 2 launch gaps; compute
//          body is byte-identical to round 8's (absmax was 0.0).
//          Fallback to the 3-kernel path if cooperative launch is refused.

#define N_PAIRS 4096
#define ZDIM    128
#define NROWS   8192
#define QS 1.6986437717f   // sqrt(2 * log2(e)) : folds 1/T=2 and exp->exp2
#define GRID_SIM 512

typedef __bf16 bf16x8 __attribute__((ext_vector_type(8)));
typedef float  floatx4 __attribute__((ext_vector_type(4)));

// ---------------------------------------------------------------------------
// Fused cooperative kernel: 512 blocks x 256 threads, 2 blocks/CU co-resident.
// ---------------------------------------------------------------------------
__global__ __launch_bounds__(256) void k_fused(
    const float* __restrict__ z1, const float* __restrict__ z2,
    __hip_bfloat16* __restrict__ pack, float* __restrict__ pos,
    float* __restrict__ denom, unsigned int* __restrict__ ctr,
    float* __restrict__ out)
{
    const int tid  = threadIdx.x;
    const int lane = tid & 63;
    const int w    = tid >> 6;
    const int q    = lane >> 4;         // quad 0..3
    const int l16  = lane & 15;
    const int b    = blockIdx.x;

    __shared__ unsigned int tk;
    __shared__ float red[4];

    // ---- phase 0: zero denom/ctr, normalize 8 pairs per block ----
    {
        const int zi = b * 256 + tid;
        if (zi < NROWS) denom[zi] = 0.0f;
        if (zi == 0) *ctr = 0u;

        #pragma unroll
        for (int pp = 0; pp < 2; ++pp) {
            const int p = b * 8 + w * 2 + pp;          // pair index < 4096
            const float2 a = ((const float2*)(z1 + (size_t)p * ZDIM))[lane];
            const float2 bb = ((const float2*)(z2 + (size_t)p * ZDIM))[lane];
            float s1 = a.x * a.x + a.y * a.y;
            float s2 = bb.x * bb.x + bb.y * bb.y;
            float d  = a.x * bb.x + a.y * bb.y;
            #pragma unroll
            for (int off = 1; off < 64; off <<= 1) {
                s1 += __shfl_xor(s1, off, 64);
                s2 += __shfl_xor(s2, off, 64);
                d  += __shfl_xor(d,  off, 64);
            }
            const float n1 = fmaxf(sqrtf(s1), 1e-8f);
            const float n2 = fmaxf(sqrtf(s2), 1e-8f);
            const float i1 = 1.0f / n1, i2 = 1.0f / n2;
            const float q1 = i1 * QS, q2 = i2 * QS;
            float2 na; na.x = a.x * q1; na.y = a.y * q1;
            float2 nb; nb.x = bb.x * q2; nb.y = bb.y * q2;

            // lane holds elements e0=2*lane, e0+1 of its row:
            //   ks = lane>>4 ; qq = (lane>>2)&3 ; jj = (lane&3)*2
            // pack elem idx for row r: ((r>>4)*4+ks)*512 + qq*128 + (r&15)*8 + jj
            const int ks = lane >> 4;
            const int qq = (lane >> 2) & 3;
            const int jj = (lane & 3) * 2;
            const int r1 = p, r2 = p + N_PAIRS;
            const size_t i1e = ((size_t)((r1 >> 4) * 4 + ks)) * 512 + qq * 128 + (r1 & 15) * 8 + jj;
            const size_t i2e = ((size_t)((r2 >> 4) * 4 + ks)) * 512 + qq * 128 + (r2 & 15) * 8 + jj;
            *(__hip_bfloat162*)(pack + i1e) = __float22bfloat162_rn(na);
            *(__hip_bfloat162*)(pack + i2e) = __float22bfloat162_rn(nb);
            if (lane == 0) pos[p] = d * i1 * i2;
        }
    }

    cg::this_grid().sync();

    // ---- phase 1: upper-triangle simsum (round-8 body, unchanged) ----
    // Unit = 256 rows x 32 cols. Row-tile rt has units ur = 0..(255-8*rt),
    // col = rt*256 + ur*32. ur<8 = diagonal band (row-only + self-mask);
    // ur>=8 strictly upper: row path AND mirrored col path.
    // 4224 units total, block b handles [33b/4, 33(b+1)/4).
    {
        int u        = (33 * b) >> 2;
        const int u1 = (33 * b + 33) >> 2;

        int rt = 0, snext = 256;            // snext = S(rt+1)
        while (u >= snext) { ++rt; snext += 256 - 8 * rt; }

        bf16x8 bufA[4][2], bufB[4][2];

        auto loadB = [&](bf16x8 (&buf)[4][2], int col) {
            const __hip_bfloat16* bp = pack + (size_t)col * 128 + lane * 8;
            #pragma unroll
            for (int ks = 0; ks < 4; ++ks)      // ks-major: first MFMA waits least
                #pragma unroll
                for (int nt = 0; nt < 2; ++nt)
                    buf[ks][nt] = *(const bf16x8*)(bp + nt * 2048 + ks * 512);
        };

        while (u < u1) {                    // per row-tile segment (1-2 iters)
            const int srt  = snext - (256 - 8 * rt);   // S(rt)
            const int uend = (u1 < snext) ? u1 : snext;
            const int rowb = rt * 256 + w * 64;

            const __hip_bfloat16* Abase = pack + (size_t)rowb * 128 + lane * 8;
            bf16x8 afrag[4][4];              // [mt][ks]
            #pragma unroll
            for (int mt = 0; mt < 4; ++mt)
                #pragma unroll
                for (int ks = 0; ks < 4; ++ks)
                    afrag[mt][ks] = *(const bf16x8*)(Abase + mt * 2048 + ks * 512);

            float rowsum[4][4];              // [mt][r]
            #pragma unroll
            for (int mt = 0; mt < 4; ++mt)
                #pragma unroll
                for (int r = 0; r < 4; ++r) rowsum[mt][r] = 0.0f;

            auto compute = [&](bf16x8 (&buf)[4][2], int ur) {
                const int  col  = rt * 256 + ur * 32;
                const bool band = (ur < 8);            // wave-uniform
                floatx4 acc[4][2];
                #pragma unroll
                for (int mt = 0; mt < 4; ++mt)
                    #pragma unroll
                    for (int nt = 0; nt < 2; ++nt) {
                        acc[mt][nt].x = 0.f; acc[mt][nt].y = 0.f;
                        acc[mt][nt].z = 0.f; acc[mt][nt].w = 0.f;
                    }
                #pragma unroll
                for (int ks = 0; ks < 4; ++ks)
                    #pragma unroll
                    for (int mt = 0; mt < 4; ++mt)
                        #pragma unroll
                        for (int nt = 0; nt < 2; ++nt)
                            acc[mt][nt] = __builtin_amdgcn_mfma_f32_16x16x32_bf16(
                                afrag[mt][ks], buf[ks][nt], acc[mt][nt], 0, 0, 0);
                // fused epilogue. C/D layout: col = l16, row = q*4 + r.
                float cp0 = 0.0f, cp1 = 0.0f;   // col-path partials per nt tile
                #pragma unroll
                for (int mt = 0; mt < 4; ++mt) {
                    const int rowtb = rowb + mt * 16;
                    #pragma unroll
                    for (int nt = 0; nt < 2; ++nt) {
                        const int coltb = col + nt * 16;
                        if (band && rowtb == coltb) {   // wave-uniform diag tile
                            #pragma unroll
                            for (int r = 0; r < 4; ++r) {
                                const float e = __builtin_amdgcn_exp2f(acc[mt][nt][r]);
                                rowsum[mt][r] += (l16 == q * 4 + r) ? 0.0f : e;
                            }
                        } else {
                            #pragma unroll
                            for (int r = 0; r < 4; ++r) {
                                const float e = __builtin_amdgcn_exp2f(acc[mt][nt][r]);
                                rowsum[mt][r] += e;
                                if (!band) { if (nt == 0) cp0 += e; else cp1 += e; }
                            }
                        }
                    }
                }
                if (!band) {
                    // col path: reduce across q -> all 64 wave rows, mirror
                    cp0 += __shfl_xor(cp0, 16, 64);
                    cp0 += __shfl_xor(cp0, 32, 64);
                    cp1 += __shfl_xor(cp1, 16, 64);
                    cp1 += __shfl_xor(cp1, 32, 64);
                    if (q == 0) {
                        atomicAdd(&denom[col + l16], cp0);
                        atomicAdd(&denom[col + 16 + l16], cp1);
                    }
                }
            };

            // double-buffered sweep over units [u, uend) of this row-tile
            int ur        = u - srt;
            const int urn = uend - srt;
            loadB(bufA, rt * 256 + ur * 32);
            while (ur + 2 <= urn) {
                loadB(bufB, rt * 256 + (ur + 1) * 32);
                compute(bufA, ur);
                int nx = ur + 2;
                if (nx >= urn) nx = urn - 1;     // clamp: preloads odd tail unit
                loadB(bufA, rt * 256 + nx * 32);
                compute(bufB, ur + 1);
                ur += 2;
            }
            if (ur < urn) compute(bufA, ur);     // odd tail

            // row-sum flush: reduce across the 16 lanes holding the same row
            #pragma unroll
            for (int mt = 0; mt < 4; ++mt)
                #pragma unroll
                for (int r = 0; r < 4; ++r) {
                    float s = rowsum[mt][r];
                    s += __shfl_xor(s, 1, 64);
                    s += __shfl_xor(s, 2, 64);
                    s += __shfl_xor(s, 4, 64);
                    s += __shfl_xor(s, 8, 64);
                    rowsum[mt][r] = s;
                }
            if (l16 == 0) {
                #pragma unroll
                for (int mt = 0; mt < 4; ++mt)
                    #pragma unroll
                    for (int r = 0; r < 4; ++r)
                        atomicAdd(&denom[rowb + mt * 16 + q * 4 + r], rowsum[mt][r]);
            }

            u = uend;
            if (u < u1) { ++rt; snext += 256 - 8 * rt; }
        }
    }

    // ---- last-block ticket: finish phase ----
    __threadfence();                       // release: my atomics ordered first
    __syncthreads();                       // whole block done before ticket
    if (tid == 0) tk = atomicAdd(ctr, 1u);
    __syncthreads();
    if (tk == GRID_SIM - 1) {
        __threadfence();                   // acquire: see everyone's atomics
        float s = 0.0f;
        for (int i = tid; i < NROWS; i += 256) s += __logf(denom[i]);
        float p = 0.0f;
        for (int i = tid; i < N_PAIRS; i += 256) p += pos[i];
        float v = s - 4.0f * p;   // sum_i pos_i/T over 2N rows = 4*sum_p cos_p
        #pragma unroll
        for (int off = 1; off < 64; off <<= 1) v += __shfl_xor(v, off, 64);
        if (lane == 0) red[w] = v;
        __syncthreads();
        if (w == 0) {
            float x = (lane < 4) ? red[lane] : 0.0f;
            x += __shfl_xor(x, 1, 64);
            x += __shfl_xor(x, 2, 64);
            if (lane == 0) out[0] = x / (float)NROWS;
        }
    }
}

// ---------------------------------------------------------------------------
// Fallback 3-kernel path (round-8 versions, used only if coop launch fails).
// ---------------------------------------------------------------------------
__global__ __launch_bounds__(256) void k_normalize(
    const float* __restrict__ z1, const float* __restrict__ z2,
    __hip_bfloat16* __restrict__ pack, float* __restrict__ pos,
    float* __restrict__ denom)
{
    const int zi = blockIdx.x * 256 + threadIdx.x;
    if (zi < NROWS) denom[zi] = 0.0f;

    const int w = threadIdx.x >> 6;
    const int lane = threadIdx.x & 63;
    const int p = blockIdx.x * 4 + w;
    const float2 a = ((const float2*)(z1 + (size_t)p * ZDIM))[lane];
    const float2 b = ((const float2*)(z2 + (size_t)p * ZDIM))[lane];
    float s1 = a.x * a.x + a.y * a.y;
    float s2 = b.x * b.x + b.y * b.y;
    float d  = a.x * b.x + a.y * b.y;
    #pragma unroll
    for (int off = 1; off < 64; off <<= 1) {
        s1 += __shfl_xor(s1, off, 64);
        s2 += __shfl_xor(s2, off, 64);
        d  += __shfl_xor(d,  off, 64);
    }
    const float n1 = fmaxf(sqrtf(s1), 1e-8f);
    const float n2 = fmaxf(sqrtf(s2), 1e-8f);
    const float i1 = 1.0f / n1, i2 = 1.0f / n2;
    const float q1 = i1 * QS, q2 = i2 * QS;
    float2 na; na.x = a.x * q1; na.y = a.y * q1;
    float2 nb; nb.x = b.x * q2; nb.y = b.y * q2;

    const int ks = lane >> 4;
    const int qq = (lane >> 2) & 3;
    const int jj = (lane & 3) * 2;
    const int r1 = p, r2 = p + N_PAIRS;
    const size_t i1e = ((size_t)((r1 >> 4) * 4 + ks)) * 512 + qq * 128 + (r1 & 15) * 8 + jj;
    const size_t i2e = ((size_t)((r2 >> 4) * 4 + ks)) * 512 + qq * 128 + (r2 & 15) * 8 + jj;
    *(__hip_bfloat162*)(pack + i1e) = __float22bfloat162_rn(na);
    *(__hip_bfloat162*)(pack + i2e) = __float22bfloat162_rn(nb);
    if (lane == 0) pos[p] = d * i1 * i2;
}

__global__ __launch_bounds__(256) void k_simsum(
    const __hip_bfloat16* __restrict__ pack, float* __restrict__ denom)
{
    const int tid  = threadIdx.x;
    const int lane = tid & 63;
    const int w    = tid >> 6;
    const int q    = lane >> 4;
    const int l16  = lane & 15;

    const int b  = blockIdx.x;
    int u        = (33 * b) >> 2;
    const int u1 = (33 * b + 33) >> 2;

    int rt = 0, snext = 256;
    while (u >= snext) { ++rt; snext += 256 - 8 * rt; }

    bf16x8 bufA[4][2], bufB[4][2];

    auto loadB = [&](bf16x8 (&buf)[4][2], int col) {
        const __hip_bfloat16* bp = pack + (size_t)col * 128 + lane * 8;
        #pragma unroll
        for (int ks = 0; ks < 4; ++ks)
            #pragma unroll
            for (int nt = 0; nt < 2; ++nt)
                buf[ks][nt] = *(const bf16x8*)(bp + nt * 2048 + ks * 512);
    };

    while (u < u1) {
        const int srt  = snext - (256 - 8 * rt);
        const int uend = (u1 < snext) ? u1 : snext;
        const int rowb = rt * 256 + w * 64;

        const __hip_bfloat16* Abase = pack + (size_t)rowb * 128 + lane * 8;
        bf16x8 afrag[4][4];
        #pragma unroll
        for (int mt = 0; mt < 4; ++mt)
            #pragma unroll
            for (int ks = 0; ks < 4; ++ks)
                afrag[mt][ks] = *(const bf16x8*)(Abase + mt * 2048 + ks * 512);

        float rowsum[4][4];
        #pragma unroll
        for (int mt = 0; mt < 4; ++mt)
            #pragma unroll
            for (int r = 0; r < 4; ++r) rowsum[mt][r] = 0.0f;

        auto compute = [&](bf16x8 (&buf)[4][2], int ur) {
            const int  col  = rt * 256 + ur * 32;
            const bool band = (ur < 8);
            floatx4 acc[4][2];
            #pragma unroll
            for (int mt = 0; mt < 4; ++mt)
                #pragma unroll
                for (int nt = 0; nt < 2; ++nt) {
                    acc[mt][nt].x = 0.f; acc[mt][nt].y = 0.f;
                    acc[mt][nt].z = 0.f; acc[mt][nt].w = 0.f;
                }
            #pragma unroll
            for (int ks = 0; ks < 4; ++ks)
                #pragma unroll
                for (int mt = 0; mt < 4; ++mt)
                    #pragma unroll
                    for (int nt = 0; nt < 2; ++nt)
                        acc[mt][nt] = __builtin_amdgcn_mfma_f32_16x16x32_bf16(
                            afrag[mt][ks], buf[ks][nt], acc[mt][nt], 0, 0, 0);
            float cp0 = 0.0f, cp1 = 0.0f;
            #pragma unroll
            for (int mt = 0; mt < 4; ++mt) {
                const int rowtb = rowb + mt * 16;
                #pragma unroll
                for (int nt = 0; nt < 2; ++nt) {
                    const int coltb = col + nt * 16;
                    if (band && rowtb == coltb) {
                        #pragma unroll
                        for (int r = 0; r < 4; ++r) {
                            const float e = __builtin_amdgcn_exp2f(acc[mt][nt][r]);
                            rowsum[mt][r] += (l16 == q * 4 + r) ? 0.0f : e;
                        }
                    } else {
                        #pragma unroll
                        for (int r = 0; r < 4; ++r) {
                            const float e = __builtin_amdgcn_exp2f(acc[mt][nt][r]);
                            rowsum[mt][r] += e;
                            if (!band) { if (nt == 0) cp0 += e; else cp1 += e; }
                        }
                    }
                }
            }
            if (!band) {
                cp0 += __shfl_xor(cp0, 16, 64);
                cp0 += __shfl_xor(cp0, 32, 64);
                cp1 += __shfl_xor(cp1, 16, 64);
                cp1 += __shfl_xor(cp1, 32, 64);
                if (q == 0) {
                    atomicAdd(&denom[col + l16], cp0);
                    atomicAdd(&denom[col + 16 + l16], cp1);
                }
            }
        };

        int ur        = u - srt;
        const int urn = uend - srt;
        loadB(bufA, rt * 256 + ur * 32);
        while (ur + 2 <= urn) {
            loadB(bufB, rt * 256 + (ur + 1) * 32);
            compute(bufA, ur);
            int nx = ur + 2;
            if (nx >= urn) nx = urn - 1;
            loadB(bufA, rt * 256 + nx * 32);
            compute(bufB, ur + 1);
            ur += 2;
        }
        if (ur < urn) compute(bufA, ur);

        #pragma unroll
        for (int mt = 0; mt < 4; ++mt)
            #pragma unroll
            for (int r = 0; r < 4; ++r) {
                float s = rowsum[mt][r];
                s += __shfl_xor(s, 1, 64);
                s += __shfl_xor(s, 2, 64);
                s += __shfl_xor(s, 4, 64);
                s += __shfl_xor(s, 8, 64);
                rowsum[mt][r] = s;
            }
        if (l16 == 0) {
            #pragma unroll
            for (int mt = 0; mt < 4; ++mt)
                #pragma unroll
                for (int r = 0; r < 4; ++r)
                    atomicAdd(&denom[rowb + mt * 16 + q * 4 + r], rowsum[mt][r]);
        }

        u = uend;
        if (u < u1) { ++rt; snext += 256 - 8 * rt; }
    }
}

__global__ __launch_bounds__(1024) void k_finish(
    const float* __restrict__ denom, const float* __restrict__ pos,
    float* __restrict__ out)
{
    __shared__ float red[16];
    const int t = threadIdx.x;
    const int lane = t & 63, wv = t >> 6;
    float s = 0.0f;
    for (int i = t; i < NROWS; i += 1024) s += __logf(denom[i]);
    float p = 0.0f;
    for (int i = t; i < N_PAIRS; i += 1024) p += pos[i];
    float v = s - 4.0f * p;
    #pragma unroll
    for (int off = 1; off < 64; off <<= 1) v += __shfl_xor(v, off, 64);
    if (lane == 0) red[wv] = v;
    __syncthreads();
    if (wv == 0) {
        float x = (lane < 16) ? red[lane] : 0.0f;
        #pragma unroll
        for (int off = 1; off < 16; off <<= 1) x += __shfl_xor(x, off, 64);
        if (lane == 0) out[0] = x / (float)NROWS;
    }
}

extern "C" void kernel_launch(void* const* d_in, const int* in_sizes, int n_in,
                              void* d_out, int out_size, void* d_ws, size_t ws_size,
                              hipStream_t stream) {
    const float* z1 = (const float*)d_in[0];
    const float* z2 = (const float*)d_in[1];
    float* out = (float*)d_out;

    char* ws = (char*)d_ws;
    __hip_bfloat16* pack = (__hip_bfloat16*)ws;                // 2 MB
    float* denom = (float*)(ws + (size_t)NROWS * ZDIM * 2);    // 32 KB
    float* pos   = denom + NROWS;                              // 16 KB
    unsigned int* ctr = (unsigned int*)(pos + N_PAIRS);        // 4 B

    void* args[] = {(void*)&z1, (void*)&z2, (void*)&pack, (void*)&pos,
                    (void*)&denom, (void*)&ctr, (void*)&out};
    hipError_t err = hipLaunchCooperativeKernel((const void*)k_fused,
                                                dim3(GRID_SIM), dim3(256),
                                                args, 0, stream);
    if (err != hipSuccess) {
        // fallback: 3-dispatch path (round-8 behavior)
        k_normalize<<<N_PAIRS / 4, 256, 0, stream>>>(z1, z2, pack, pos, denom);
        k_simsum<<<GRID_SIM, 256, 0, stream>>>(pack, denom);
        k_finish<<<1, 1024, 0, stream>>>(denom, pos, out);
    }
}

// Round 4
// 114.982 us; speedup vs baseline: 1.4553x; 1.4553x over previous
//
#include <hip/hip_runtime.h>
#include <hip/hip_bf16.h>

// NT-Xent loss, N=4096, Z=128, T=0.5.
//
// Round 7: fragment-order pack + 64-row waves + reg-dbuf B: simsum ~10 us.
// Round 8: upper-triangle symmetry (row + mirrored col path): ~6-7 us.
//          Window = 42 us harness poison-fill + ~7-12 us per dispatch
//          boundary; kernels are small.
// Round 9: cooperative grid.sync REGRESSED (101 us: per-block agent fences).
// Round 10: single-dispatch with spin-gates -> container died twice (hang or
//          infra; indistinguishable). Lesson: no unbounded device spins, no
//          three-new-mechanisms-at-once bets.
// Round 11: SAFE COMPOSITION of proven parts, 2 dispatches, ZERO spins:
//   k_normalize  (round-1 verbatim; also zeroes denom + ticket counter)
//   k_simfin     (round-8 simsum body verbatim + round-2's validated
//                 no-spin ticket tail: last ticket holder -- who by
//                 construction runs after all other blocks' release fences
//                 and increments -- does the log/pos reduction in-place).
// Removes one dispatch boundary and the separate finish dispatch.

#define N_PAIRS 4096
#define ZDIM    128
#define NROWS   8192
#define QS 1.6986437717f   // sqrt(2 * log2(e)) : folds 1/T=2 and exp->exp2
#define GRID 512

typedef __bf16 bf16x8 __attribute__((ext_vector_type(8)));
typedef float  floatx4 __attribute__((ext_vector_type(4)));

__global__ __launch_bounds__(256) void k_normalize(
    const float* __restrict__ z1, const float* __restrict__ z2,
    __hip_bfloat16* __restrict__ pack, float* __restrict__ pos,
    float* __restrict__ denom, unsigned int* __restrict__ dctr)
{
    const int zi = blockIdx.x * 256 + threadIdx.x;   // grid 1024 blocks
    if (zi < NROWS) denom[zi] = 0.0f;
    if (zi == 0) *dctr = 0u;

    const int w = threadIdx.x >> 6;
    const int lane = threadIdx.x & 63;
    const int p = blockIdx.x * 4 + w;            // pair index, < 4096
    const float2 a = ((const float2*)(z1 + (size_t)p * ZDIM))[lane];
    const float2 b = ((const float2*)(z2 + (size_t)p * ZDIM))[lane];
    float s1 = a.x * a.x + a.y * a.y;
    float s2 = b.x * b.x + b.y * b.y;
    float d  = a.x * b.x + a.y * b.y;
    #pragma unroll
    for (int off = 1; off < 64; off <<= 1) {
        s1 += __shfl_xor(s1, off, 64);
        s2 += __shfl_xor(s2, off, 64);
        d  += __shfl_xor(d,  off, 64);
    }
    const float n1 = fmaxf(sqrtf(s1), 1e-8f);
    const float n2 = fmaxf(sqrtf(s2), 1e-8f);
    const float i1 = 1.0f / n1, i2 = 1.0f / n2;
    const float q1 = i1 * QS, q2 = i2 * QS;
    float2 na; na.x = a.x * q1; na.y = a.y * q1;
    float2 nb; nb.x = b.x * q2; nb.y = b.y * q2;

    // lane holds elements e0=2*lane, e0+1 of its row:
    //   ks = lane>>4 ; q = (lane>>2)&3 ; j = (lane&3)*2
    // pack elem idx for row r: ((r>>4)*4 + ks)*512 + q*128 + (r&15)*8 + j
    const int ks = lane >> 4;
    const int qq = (lane >> 2) & 3;
    const int jj = (lane & 3) * 2;
    const int r1 = p, r2 = p + N_PAIRS;
    const size_t i1e = ((size_t)((r1 >> 4) * 4 + ks)) * 512 + qq * 128 + (r1 & 15) * 8 + jj;
    const size_t i2e = ((size_t)((r2 >> 4) * 4 + ks)) * 512 + qq * 128 + (r2 & 15) * 8 + jj;
    *(__hip_bfloat162*)(pack + i1e) = __float22bfloat162_rn(na);
    *(__hip_bfloat162*)(pack + i2e) = __float22bfloat162_rn(nb);
    if (lane == 0) pos[p] = d * i1 * i2;
}

// Upper-triangle strip schedule (round-8, verified).
// Unit = 256 rows x 32 cols. Row-tile rt has units ur = 0..(255-8*rt),
// col = rt*256 + ur*32. ur<8 = diagonal band (row-only + self-mask);
// ur>=8 strictly upper: row path AND mirrored col path.
// 4224 units total; block b handles [33b/4, 33(b+1)/4).
// Tail: no-spin ticket -- last incrementer does the finish reduction.
__global__ __launch_bounds__(256) void k_simfin(
    const __hip_bfloat16* __restrict__ pack, float* __restrict__ denom,
    const float* __restrict__ pos, unsigned int* __restrict__ dctr,
    float* __restrict__ out)
{
    __shared__ unsigned int tk;
    __shared__ float red[4];

    const int tid  = threadIdx.x;
    const int lane = tid & 63;
    const int w    = tid >> 6;
    const int q    = lane >> 4;         // quad 0..3
    const int l16  = lane & 15;

    const int b  = blockIdx.x;
    int u        = (33 * b) >> 2;       // first global unit
    const int u1 = (33 * b + 33) >> 2;  // one past last

    // S(rt) = 256*rt - 4*rt*(rt-1); find rt with S(rt) <= u < S(rt+1)
    int rt = 0, snext = 256;            // snext = S(rt+1)
    while (u >= snext) { ++rt; snext += 256 - 8 * rt; }

    bf16x8 bufA[4][2], bufB[4][2];

    auto loadB = [&](bf16x8 (&buf)[4][2], int col) {
        const __hip_bfloat16* bp = pack + (size_t)col * 128 + lane * 8;
        #pragma unroll
        for (int ks = 0; ks < 4; ++ks)      // ks-major: first MFMA waits least
            #pragma unroll
            for (int nt = 0; nt < 2; ++nt)
                buf[ks][nt] = *(const bf16x8*)(bp + nt * 2048 + ks * 512);
    };

    while (u < u1) {                    // per row-tile segment (1-2 iterations)
        const int srt  = snext - (256 - 8 * rt);   // S(rt)
        const int uend = (u1 < snext) ? u1 : snext;
        const int rowb = rt * 256 + w * 64;

        // persistent A fragments: wave's 64 rows x full K=128 (64 VGPRs)
        const __hip_bfloat16* Abase = pack + (size_t)rowb * 128 + lane * 8;
        bf16x8 afrag[4][4];              // [mt][ks]
        #pragma unroll
        for (int mt = 0; mt < 4; ++mt)
            #pragma unroll
            for (int ks = 0; ks < 4; ++ks)
                afrag[mt][ks] = *(const bf16x8*)(Abase + mt * 2048 + ks * 512);

        float rowsum[4][4];              // [mt][r]
        #pragma unroll
        for (int mt = 0; mt < 4; ++mt)
            #pragma unroll
            for (int r = 0; r < 4; ++r) rowsum[mt][r] = 0.0f;

        auto compute = [&](bf16x8 (&buf)[4][2], int ur) {
            const int  col  = rt * 256 + ur * 32;
            const bool band = (ur < 8);            // wave-uniform
            floatx4 acc[4][2];
            #pragma unroll
            for (int mt = 0; mt < 4; ++mt)
                #pragma unroll
                for (int nt = 0; nt < 2; ++nt) {
                    acc[mt][nt].x = 0.f; acc[mt][nt].y = 0.f;
                    acc[mt][nt].z = 0.f; acc[mt][nt].w = 0.f;
                }
            #pragma unroll
            for (int ks = 0; ks < 4; ++ks)
                #pragma unroll
                for (int mt = 0; mt < 4; ++mt)
                    #pragma unroll
                    for (int nt = 0; nt < 2; ++nt)
                        acc[mt][nt] = __builtin_amdgcn_mfma_f32_16x16x32_bf16(
                            afrag[mt][ks], buf[ks][nt], acc[mt][nt], 0, 0, 0);
            // fused epilogue. C/D layout: col = l16, row = q*4 + r (m89/m91).
            float cp0 = 0.0f, cp1 = 0.0f;   // col-path partials per nt tile
            #pragma unroll
            for (int mt = 0; mt < 4; ++mt) {
                const int rowtb = rowb + mt * 16;
                #pragma unroll
                for (int nt = 0; nt < 2; ++nt) {
                    const int coltb = col + nt * 16;
                    if (band && rowtb == coltb) {   // wave-uniform: diag tile
                        #pragma unroll
                        for (int r = 0; r < 4; ++r) {
                            const float e = __builtin_amdgcn_exp2f(acc[mt][nt][r]);
                            rowsum[mt][r] += (l16 == q * 4 + r) ? 0.0f : e;
                        }
                    } else {
                        #pragma unroll
                        for (int r = 0; r < 4; ++r) {
                            const float e = __builtin_amdgcn_exp2f(acc[mt][nt][r]);
                            rowsum[mt][r] += e;
                            if (!band) { if (nt == 0) cp0 += e; else cp1 += e; }
                        }
                    }
                }
            }
            if (!band) {
                // col path: reduce across q -> all 64 wave rows, then mirror
                cp0 += __shfl_xor(cp0, 16, 64);
                cp0 += __shfl_xor(cp0, 32, 64);
                cp1 += __shfl_xor(cp1, 16, 64);
                cp1 += __shfl_xor(cp1, 32, 64);
                if (q == 0) {
                    atomicAdd(&denom[col + l16], cp0);
                    atomicAdd(&denom[col + 16 + l16], cp1);
                }
            }
        };

        // double-buffered sweep over units [u, uend) of this row-tile
        int ur        = u - srt;
        const int urn = uend - srt;
        loadB(bufA, rt * 256 + ur * 32);
        while (ur + 2 <= urn) {
            loadB(bufB, rt * 256 + (ur + 1) * 32);
            compute(bufA, ur);
            int nx = ur + 2;
            if (nx >= urn) nx = urn - 1;     // clamp: preloads odd tail unit
            loadB(bufA, rt * 256 + nx * 32);
            compute(bufB, ur + 1);
            ur += 2;
        }
        if (ur < urn) compute(bufA, ur);     // odd tail (bufA holds its cols)

        // row-sum flush: reduce across the 16 lanes holding the same row
        #pragma unroll
        for (int mt = 0; mt < 4; ++mt)
            #pragma unroll
            for (int r = 0; r < 4; ++r) {
                float s = rowsum[mt][r];
                s += __shfl_xor(s, 1, 64);
                s += __shfl_xor(s, 2, 64);
                s += __shfl_xor(s, 4, 64);
                s += __shfl_xor(s, 8, 64);
                rowsum[mt][r] = s;
            }
        if (l16 == 0) {
            #pragma unroll
            for (int mt = 0; mt < 4; ++mt)
                #pragma unroll
                for (int r = 0; r < 4; ++r)
                    atomicAdd(&denom[rowb + mt * 16 + q * 4 + r], rowsum[mt][r]);
        }

        u = uend;
        if (u < u1) { ++rt; snext += 256 - 8 * rt; }
    }

    // ---- no-spin ticket finish (validated in round 2) ----
    __threadfence();                   // release: my atomics/stores ordered
    __syncthreads();                   // whole block done before ticket
    if (tid == 0) tk = atomicAdd(dctr, 1u);
    __syncthreads();
    if (tk == GRID - 1) {              // all other blocks already released
        __threadfence();               // acquire: see everyone's updates
        float s = 0.0f;
        for (int i = tid; i < NROWS; i += 256) s += __logf(denom[i]);
        float p = 0.0f;
        for (int i = tid; i < N_PAIRS; i += 256) p += pos[i];
        float v = s - 4.0f * p;   // sum_i pos_i/T over 2N rows = 4*sum_p cos_p
        #pragma unroll
        for (int off = 1; off < 64; off <<= 1) v += __shfl_xor(v, off, 64);
        if (lane == 0) red[w] = v;
        __syncthreads();
        if (w == 0) {
            float x = (lane < 4) ? red[lane] : 0.0f;
            x += __shfl_xor(x, 1, 64);
            x += __shfl_xor(x, 2, 64);
            if (lane == 0) out[0] = x / (float)NROWS;
        }
    }
}

extern "C" void kernel_launch(void* const* d_in, const int* in_sizes, int n_in,
                              void* d_out, int out_size, void* d_ws, size_t ws_size,
                              hipStream_t stream) {
    const float* z1 = (const float*)d_in[0];
    const float* z2 = (const float*)d_in[1];
    float* out = (float*)d_out;

    char* ws = (char*)d_ws;
    __hip_bfloat16* pack = (__hip_bfloat16*)ws;                // 2 MB
    float* denom = (float*)(ws + (size_t)NROWS * ZDIM * 2);    // 32 KB
    float* pos   = denom + NROWS;                              // 16 KB
    unsigned int* dctr = (unsigned int*)(pos + N_PAIRS);       // 4 B

    k_normalize<<<N_PAIRS / 4, 256, 0, stream>>>(z1, z2, pack, pos, denom, dctr);
    k_simfin<<<GRID, 256, 0, stream>>>(pack, denom, pos, dctr, out);
}

// Round 5
// 90.347 us; speedup vs baseline: 1.8522x; 1.2727x over previous
//
#include <hip/hip_runtime.h>
#include <hip/hip_bf16.h>

// NT-Xent loss, N=4096, Z=128, T=0.5.
//
// Round 7: fragment-order pack + 64-row waves + reg-dbuf B: simsum ~10 us.
// Round 8: upper-triangle symmetry (row + mirrored col path): ~6-7 us.
// Round 9: cooperative grid.sync REGRESSED (101 us).
// Round 10: spin-gated single dispatch -> container died twice.
// Round 11 (round 4 bench): 2 dispatches + ticket tail with __threadfence:
//          k_simfin 60.5 us, MfmaUtil 5.3% -> compute still ~11 us, the
//          ticket tail's per-block __threadfence (whole-L2 wbl2/inv, x512
//          blocks, serialized per XCD) cost ~48 us. Gaps measured ~3.7 us.
//          LESSON: never issue per-block device-scope fences on gfx950.
// Round 12: SAME structure, fence-free ticket:
//          - denom is updated ONLY by device-scope atomics -> completion is
//            tracked by vmcnt at the coherent point (LLC). Release =
//            s_waitcnt vmcnt(0) + __syncthreads() (each wave drains its own
//            counter), then one ticket atomicAdd. No cache-walk ops.
//          - last ticket holder reads denom with agent-scope RELAXED atomic
//            loads (bypass non-coherent L1/L2; rocPRIM decoupled-lookback
//            pattern), pos with plain loads (prev dispatch, boundary-flushed).
//          No spins: hang-proof by construction.

#define N_PAIRS 4096
#define ZDIM    128
#define NROWS   8192
#define QS 1.6986437717f   // sqrt(2 * log2(e)) : folds 1/T=2 and exp->exp2
#define GRID 512

typedef __bf16 bf16x8 __attribute__((ext_vector_type(8)));
typedef float  floatx4 __attribute__((ext_vector_type(4)));

__global__ __launch_bounds__(256) void k_normalize(
    const float* __restrict__ z1, const float* __restrict__ z2,
    __hip_bfloat16* __restrict__ pack, float* __restrict__ pos,
    float* __restrict__ denom, unsigned int* __restrict__ dctr)
{
    const int zi = blockIdx.x * 256 + threadIdx.x;   // grid 1024 blocks
    if (zi < NROWS) denom[zi] = 0.0f;
    if (zi == 0) *dctr = 0u;

    const int w = threadIdx.x >> 6;
    const int lane = threadIdx.x & 63;
    const int p = blockIdx.x * 4 + w;            // pair index, < 4096
    const float2 a = ((const float2*)(z1 + (size_t)p * ZDIM))[lane];
    const float2 b = ((const float2*)(z2 + (size_t)p * ZDIM))[lane];
    float s1 = a.x * a.x + a.y * a.y;
    float s2 = b.x * b.x + b.y * b.y;
    float d  = a.x * b.x + a.y * b.y;
    #pragma unroll
    for (int off = 1; off < 64; off <<= 1) {
        s1 += __shfl_xor(s1, off, 64);
        s2 += __shfl_xor(s2, off, 64);
        d  += __shfl_xor(d,  off, 64);
    }
    const float n1 = fmaxf(sqrtf(s1), 1e-8f);
    const float n2 = fmaxf(sqrtf(s2), 1e-8f);
    const float i1 = 1.0f / n1, i2 = 1.0f / n2;
    const float q1 = i1 * QS, q2 = i2 * QS;
    float2 na; na.x = a.x * q1; na.y = a.y * q1;
    float2 nb; nb.x = b.x * q2; nb.y = b.y * q2;

    // lane holds elements e0=2*lane, e0+1 of its row:
    //   ks = lane>>4 ; q = (lane>>2)&3 ; j = (lane&3)*2
    // pack elem idx for row r: ((r>>4)*4 + ks)*512 + q*128 + (r&15)*8 + j
    const int ks = lane >> 4;
    const int qq = (lane >> 2) & 3;
    const int jj = (lane & 3) * 2;
    const int r1 = p, r2 = p + N_PAIRS;
    const size_t i1e = ((size_t)((r1 >> 4) * 4 + ks)) * 512 + qq * 128 + (r1 & 15) * 8 + jj;
    const size_t i2e = ((size_t)((r2 >> 4) * 4 + ks)) * 512 + qq * 128 + (r2 & 15) * 8 + jj;
    *(__hip_bfloat162*)(pack + i1e) = __float22bfloat162_rn(na);
    *(__hip_bfloat162*)(pack + i2e) = __float22bfloat162_rn(nb);
    if (lane == 0) pos[p] = d * i1 * i2;
}

// Upper-triangle strip schedule (round-8, verified).
// Unit = 256 rows x 32 cols. Row-tile rt has units ur = 0..(255-8*rt),
// col = rt*256 + ur*32. ur<8 = diagonal band (row-only + self-mask);
// ur>=8 strictly upper: row path AND mirrored col path.
// 4224 units total; block b handles [33b/4, 33(b+1)/4).
// Tail: fence-free ticket -- last incrementer does the finish reduction.
__global__ __launch_bounds__(256) void k_simfin(
    const __hip_bfloat16* __restrict__ pack, float* __restrict__ denom,
    const float* __restrict__ pos, unsigned int* __restrict__ dctr,
    float* __restrict__ out)
{
    __shared__ unsigned int tk;
    __shared__ float red[4];

    const int tid  = threadIdx.x;
    const int lane = tid & 63;
    const int w    = tid >> 6;
    const int q    = lane >> 4;         // quad 0..3
    const int l16  = lane & 15;

    const int b  = blockIdx.x;
    int u        = (33 * b) >> 2;       // first global unit
    const int u1 = (33 * b + 33) >> 2;  // one past last

    // S(rt) = 256*rt - 4*rt*(rt-1); find rt with S(rt) <= u < S(rt+1)
    int rt = 0, snext = 256;            // snext = S(rt+1)
    while (u >= snext) { ++rt; snext += 256 - 8 * rt; }

    bf16x8 bufA[4][2], bufB[4][2];

    auto loadB = [&](bf16x8 (&buf)[4][2], int col) {
        const __hip_bfloat16* bp = pack + (size_t)col * 128 + lane * 8;
        #pragma unroll
        for (int ks = 0; ks < 4; ++ks)      // ks-major: first MFMA waits least
            #pragma unroll
            for (int nt = 0; nt < 2; ++nt)
                buf[ks][nt] = *(const bf16x8*)(bp + nt * 2048 + ks * 512);
    };

    while (u < u1) {                    // per row-tile segment (1-2 iterations)
        const int srt  = snext - (256 - 8 * rt);   // S(rt)
        const int uend = (u1 < snext) ? u1 : snext;
        const int rowb = rt * 256 + w * 64;

        // persistent A fragments: wave's 64 rows x full K=128 (64 VGPRs)
        const __hip_bfloat16* Abase = pack + (size_t)rowb * 128 + lane * 8;
        bf16x8 afrag[4][4];              // [mt][ks]
        #pragma unroll
        for (int mt = 0; mt < 4; ++mt)
            #pragma unroll
            for (int ks = 0; ks < 4; ++ks)
                afrag[mt][ks] = *(const bf16x8*)(Abase + mt * 2048 + ks * 512);

        float rowsum[4][4];              // [mt][r]
        #pragma unroll
        for (int mt = 0; mt < 4; ++mt)
            #pragma unroll
            for (int r = 0; r < 4; ++r) rowsum[mt][r] = 0.0f;

        auto compute = [&](bf16x8 (&buf)[4][2], int ur) {
            const int  col  = rt * 256 + ur * 32;
            const bool band = (ur < 8);            // wave-uniform
            floatx4 acc[4][2];
            #pragma unroll
            for (int mt = 0; mt < 4; ++mt)
                #pragma unroll
                for (int nt = 0; nt < 2; ++nt) {
                    acc[mt][nt].x = 0.f; acc[mt][nt].y = 0.f;
                    acc[mt][nt].z = 0.f; acc[mt][nt].w = 0.f;
                }
            #pragma unroll
            for (int ks = 0; ks < 4; ++ks)
                #pragma unroll
                for (int mt = 0; mt < 4; ++mt)
                    #pragma unroll
                    for (int nt = 0; nt < 2; ++nt)
                        acc[mt][nt] = __builtin_amdgcn_mfma_f32_16x16x32_bf16(
                            afrag[mt][ks], buf[ks][nt], acc[mt][nt], 0, 0, 0);
            // fused epilogue. C/D layout: col = l16, row = q*4 + r (m89/m91).
            float cp0 = 0.0f, cp1 = 0.0f;   // col-path partials per nt tile
            #pragma unroll
            for (int mt = 0; mt < 4; ++mt) {
                const int rowtb = rowb + mt * 16;
                #pragma unroll
                for (int nt = 0; nt < 2; ++nt) {
                    const int coltb = col + nt * 16;
                    if (band && rowtb == coltb) {   // wave-uniform: diag tile
                        #pragma unroll
                        for (int r = 0; r < 4; ++r) {
                            const float e = __builtin_amdgcn_exp2f(acc[mt][nt][r]);
                            rowsum[mt][r] += (l16 == q * 4 + r) ? 0.0f : e;
                        }
                    } else {
                        #pragma unroll
                        for (int r = 0; r < 4; ++r) {
                            const float e = __builtin_amdgcn_exp2f(acc[mt][nt][r]);
                            rowsum[mt][r] += e;
                            if (!band) { if (nt == 0) cp0 += e; else cp1 += e; }
                        }
                    }
                }
            }
            if (!band) {
                // col path: reduce across q -> all 64 wave rows, then mirror
                cp0 += __shfl_xor(cp0, 16, 64);
                cp0 += __shfl_xor(cp0, 32, 64);
                cp1 += __shfl_xor(cp1, 16, 64);
                cp1 += __shfl_xor(cp1, 32, 64);
                if (q == 0) {
                    atomicAdd(&denom[col + l16], cp0);
                    atomicAdd(&denom[col + 16 + l16], cp1);
                }
            }
        };

        // double-buffered sweep over units [u, uend) of this row-tile
        int ur        = u - srt;
        const int urn = uend - srt;
        loadB(bufA, rt * 256 + ur * 32);
        while (ur + 2 <= urn) {
            loadB(bufB, rt * 256 + (ur + 1) * 32);
            compute(bufA, ur);
            int nx = ur + 2;
            if (nx >= urn) nx = urn - 1;     // clamp: preloads odd tail unit
            loadB(bufA, rt * 256 + nx * 32);
            compute(bufB, ur + 1);
            ur += 2;
        }
        if (ur < urn) compute(bufA, ur);     // odd tail (bufA holds its cols)

        // row-sum flush: reduce across the 16 lanes holding the same row
        #pragma unroll
        for (int mt = 0; mt < 4; ++mt)
            #pragma unroll
            for (int r = 0; r < 4; ++r) {
                float s = rowsum[mt][r];
                s += __shfl_xor(s, 1, 64);
                s += __shfl_xor(s, 2, 64);
                s += __shfl_xor(s, 4, 64);
                s += __shfl_xor(s, 8, 64);
                rowsum[mt][r] = s;
            }
        if (l16 == 0) {
            #pragma unroll
            for (int mt = 0; mt < 4; ++mt)
                #pragma unroll
                for (int r = 0; r < 4; ++r)
                    atomicAdd(&denom[rowb + mt * 16 + q * 4 + r], rowsum[mt][r]);
        }

        u = uend;
        if (u < u1) { ++rt; snext += 256 - 8 * rt; }
    }

    // ---- fence-free ticket finish ----
    // All denom updates are device-scope atomics: vmcnt tracks their
    // completion at the coherent point. Drain own vmcnt, barrier (so every
    // wave of this block has drained), then ticket. NO __threadfence --
    // round-4 showed per-block wbl2/inv costs ~48 us across 512 blocks.
    asm volatile("s_waitcnt vmcnt(0)" ::: "memory");
    __syncthreads();
    if (tid == 0) tk = atomicAdd(dctr, 1u);
    __syncthreads();
    if (tk == GRID - 1) {              // 511 prior increments, each after that
                                       // block's denom atomics hit LLC
        float s = 0.0f;
        for (int i = tid; i < NROWS; i += 256) {
            const float dv = __hip_atomic_load(&denom[i], __ATOMIC_RELAXED,
                                               __HIP_MEMORY_SCOPE_AGENT);
            s += __logf(dv);
        }
        float p = 0.0f;
        for (int i = tid; i < N_PAIRS; i += 256) p += pos[i];
        float v = s - 4.0f * p;   // sum_i pos_i/T over 2N rows = 4*sum_p cos_p
        #pragma unroll
        for (int off = 1; off < 64; off <<= 1) v += __shfl_xor(v, off, 64);
        if (lane == 0) red[w] = v;
        __syncthreads();
        if (w == 0) {
            float x = (lane < 4) ? red[lane] : 0.0f;
            x += __shfl_xor(x, 1, 64);
            x += __shfl_xor(x, 2, 64);
            if (lane == 0) out[0] = x / (float)NROWS;
        }
    }
}

extern "C" void kernel_launch(void* const* d_in, const int* in_sizes, int n_in,
                              void* d_out, int out_size, void* d_ws, size_t ws_size,
                              hipStream_t stream) {
    const float* z1 = (const float*)d_in[0];
    const float* z2 = (const float*)d_in[1];
    float* out = (float*)d_out;

    char* ws = (char*)d_ws;
    __hip_bfloat16* pack = (__hip_bfloat16*)ws;                // 2 MB
    float* denom = (float*)(ws + (size_t)NROWS * ZDIM * 2);    // 32 KB
    float* pos   = denom + NROWS;                              // 16 KB
    unsigned int* dctr = (unsigned int*)(pos + N_PAIRS);       // 4 B

    k_normalize<<<N_PAIRS / 4, 256, 0, stream>>>(z1, z2, pack, pos, denom, dctr);
    k_simfin<<<GRID, 256, 0, stream>>>(pack, denom, pos, dctr, out);
}

// Round 6
// 89.339 us; speedup vs baseline: 1.8731x; 1.0113x over previous
//
#include <hip/hip_runtime.h>
#include <hip/hip_bf16.h>

// NT-Xent loss, N=4096, Z=128, T=0.5.
//
// Round 7: fragment-order pack + 64-row waves + reg-dbuf B.
// Round 8: upper-triangle symmetry (row + mirrored col path). PASSED 82.1us.
// Round 9: cooperative grid.sync REGRESSED (101 us; per-block agent fences).
// Round 10: spin-gated single dispatch -> container died. No device spins.
// Round 11: ticket tail with __threadfence: k_simfin 60.5us. Fence = whole-L2
//          wb/inv per block x512 ~= 48us. EXACT decomposition established:
//          gap=3.7us, fill=42us, norm=1.5us.
// Round 12: fence-free ticket: tail still 14.3us (vs 6.2us for gap+finish
//          dispatch) -> TICKET LOSES. Also: triangle compute = ~21us with
//          MFMA busy only ~4us, VALU ~6us -> LATENCY-BOUND at 8 waves/CU
//          (grid 512 = 2 blocks/CU was the cap, not VGPR=128).
// Round 13 (this): revert to the PROVEN 3-dispatch round-8 structure;
//          ONE change: k_simsum grid 512 -> 1024 (4 blocks/CU, 16 waves/CU).
//          Strip partition [33b/8, 33(b+1)/8) = 4-5 units/block (still
//          pipelined via reg-dbuf; not the 2-unit latency regime).
//
//  k_normalize: row-normalize (fp32), quantize bf16 scaled by
//               QS = sqrt(2*log2(e)) (folds 1/T=2 and exp->exp2), write in
//               fragment order; exact fp32 pair-cosines pos[4096]; zero denom.
//  k_simsum:    denom[i] = sum_{j!=i} exp(2*sim_ij), triangle + mirror.
//  k_finish:    out = (sum_i log denom_i - 4 * sum_p pos_p) / 8192

#define N_PAIRS 4096
#define ZDIM    128
#define NROWS   8192
#define QS 1.6986437717f   // sqrt(2 * log2(e))
#define GRID_SIM 1024

typedef __bf16 bf16x8 __attribute__((ext_vector_type(8)));
typedef float  floatx4 __attribute__((ext_vector_type(4)));

__global__ __launch_bounds__(256) void k_normalize(
    const float* __restrict__ z1, const float* __restrict__ z2,
    __hip_bfloat16* __restrict__ pack, float* __restrict__ pos,
    float* __restrict__ denom)
{
    const int zi = blockIdx.x * 256 + threadIdx.x;   // grid 1024 blocks
    if (zi < NROWS) denom[zi] = 0.0f;

    const int w = threadIdx.x >> 6;
    const int lane = threadIdx.x & 63;
    const int p = blockIdx.x * 4 + w;            // pair index, < 4096
    const float2 a = ((const float2*)(z1 + (size_t)p * ZDIM))[lane];
    const float2 b = ((const float2*)(z2 + (size_t)p * ZDIM))[lane];
    float s1 = a.x * a.x + a.y * a.y;
    float s2 = b.x * b.x + b.y * b.y;
    float d  = a.x * b.x + a.y * b.y;
    #pragma unroll
    for (int off = 1; off < 64; off <<= 1) {
        s1 += __shfl_xor(s1, off, 64);
        s2 += __shfl_xor(s2, off, 64);
        d  += __shfl_xor(d,  off, 64);
    }
    const float n1 = fmaxf(sqrtf(s1), 1e-8f);
    const float n2 = fmaxf(sqrtf(s2), 1e-8f);
    const float i1 = 1.0f / n1, i2 = 1.0f / n2;
    const float q1 = i1 * QS, q2 = i2 * QS;
    float2 na; na.x = a.x * q1; na.y = a.y * q1;
    float2 nb; nb.x = b.x * q2; nb.y = b.y * q2;

    // lane holds elements e0=2*lane, e0+1 of its row:
    //   ks = lane>>4 ; q = (lane>>2)&3 ; j = (lane&3)*2
    // pack elem idx for row r: ((r>>4)*4 + ks)*512 + q*128 + (r&15)*8 + j
    const int ks = lane >> 4;
    const int qq = (lane >> 2) & 3;
    const int jj = (lane & 3) * 2;
    const int r1 = p, r2 = p + N_PAIRS;
    const size_t i1e = ((size_t)((r1 >> 4) * 4 + ks)) * 512 + qq * 128 + (r1 & 15) * 8 + jj;
    const size_t i2e = ((size_t)((r2 >> 4) * 4 + ks)) * 512 + qq * 128 + (r2 & 15) * 8 + jj;
    *(__hip_bfloat162*)(pack + i1e) = __float22bfloat162_rn(na);
    *(__hip_bfloat162*)(pack + i2e) = __float22bfloat162_rn(nb);
    if (lane == 0) pos[p] = d * i1 * i2;
}

// Upper-triangle strip schedule (round-8 verified math).
// Unit = 256 rows x 32 cols. Row-tile rt has units ur = 0..(255-8*rt),
// col = rt*256 + ur*32. ur<8 = diagonal band (row-only + self-mask);
// ur>=8 strictly upper: row path AND mirrored col path.
// 4224 units; block b of 1024 handles [33b/8, 33(b+1)/8) = 4-5 units.
__global__ __launch_bounds__(256) void k_simsum(
    const __hip_bfloat16* __restrict__ pack, float* __restrict__ denom)
{
    const int tid  = threadIdx.x;
    const int lane = tid & 63;
    const int w    = tid >> 6;
    const int q    = lane >> 4;         // quad 0..3
    const int l16  = lane & 15;

    const int b  = blockIdx.x;
    int u        = (33 * b) >> 3;       // first global unit
    const int u1 = (33 * b + 33) >> 3;  // one past last

    // S(rt) = 256*rt - 4*rt*(rt-1); find rt with S(rt) <= u < S(rt+1)
    int rt = 0, snext = 256;            // snext = S(rt+1)
    while (u >= snext) { ++rt; snext += 256 - 8 * rt; }

    bf16x8 bufA[4][2], bufB[4][2];

    auto loadB = [&](bf16x8 (&buf)[4][2], int col) {
        const __hip_bfloat16* bp = pack + (size_t)col * 128 + lane * 8;
        #pragma unroll
        for (int ks = 0; ks < 4; ++ks)      // ks-major: first MFMA waits least
            #pragma unroll
            for (int nt = 0; nt < 2; ++nt)
                buf[ks][nt] = *(const bf16x8*)(bp + nt * 2048 + ks * 512);
    };

    while (u < u1) {                    // per row-tile segment (1-2 iterations)
        const int srt  = snext - (256 - 8 * rt);   // S(rt)
        const int uend = (u1 < snext) ? u1 : snext;
        const int rowb = rt * 256 + w * 64;

        // persistent A fragments: wave's 64 rows x full K=128 (64 VGPRs)
        const __hip_bfloat16* Abase = pack + (size_t)rowb * 128 + lane * 8;
        bf16x8 afrag[4][4];              // [mt][ks]
        #pragma unroll
        for (int mt = 0; mt < 4; ++mt)
            #pragma unroll
            for (int ks = 0; ks < 4; ++ks)
                afrag[mt][ks] = *(const bf16x8*)(Abase + mt * 2048 + ks * 512);

        float rowsum[4][4];              // [mt][r]
        #pragma unroll
        for (int mt = 0; mt < 4; ++mt)
            #pragma unroll
            for (int r = 0; r < 4; ++r) rowsum[mt][r] = 0.0f;

        auto compute = [&](bf16x8 (&buf)[4][2], int ur) {
            const int  col  = rt * 256 + ur * 32;
            const bool band = (ur < 8);            // wave-uniform
            floatx4 acc[4][2];
            #pragma unroll
            for (int mt = 0; mt < 4; ++mt)
                #pragma unroll
                for (int nt = 0; nt < 2; ++nt) {
                    acc[mt][nt].x = 0.f; acc[mt][nt].y = 0.f;
                    acc[mt][nt].z = 0.f; acc[mt][nt].w = 0.f;
                }
            #pragma unroll
            for (int ks = 0; ks < 4; ++ks)
                #pragma unroll
                for (int mt = 0; mt < 4; ++mt)
                    #pragma unroll
                    for (int nt = 0; nt < 2; ++nt)
                        acc[mt][nt] = __builtin_amdgcn_mfma_f32_16x16x32_bf16(
                            afrag[mt][ks], buf[ks][nt], acc[mt][nt], 0, 0, 0);
            // fused epilogue. C/D layout: col = l16, row = q*4 + r (m89/m91).
            float cp0 = 0.0f, cp1 = 0.0f;   // col-path partials per nt tile
            #pragma unroll
            for (int mt = 0; mt < 4; ++mt) {
                const int rowtb = rowb + mt * 16;
                #pragma unroll
                for (int nt = 0; nt < 2; ++nt) {
                    const int coltb = col + nt * 16;
                    if (band && rowtb == coltb) {   // wave-uniform: diag tile
                        #pragma unroll
                        for (int r = 0; r < 4; ++r) {
                            const float e = __builtin_amdgcn_exp2f(acc[mt][nt][r]);
                            rowsum[mt][r] += (l16 == q * 4 + r) ? 0.0f : e;
                        }
                    } else {
                        #pragma unroll
                        for (int r = 0; r < 4; ++r) {
                            const float e = __builtin_amdgcn_exp2f(acc[mt][nt][r]);
                            rowsum[mt][r] += e;
                            if (!band) { if (nt == 0) cp0 += e; else cp1 += e; }
                        }
                    }
                }
            }
            if (!band) {
                // col path: reduce across q -> all 64 wave rows, then mirror
                cp0 += __shfl_xor(cp0, 16, 64);
                cp0 += __shfl_xor(cp0, 32, 64);
                cp1 += __shfl_xor(cp1, 16, 64);
                cp1 += __shfl_xor(cp1, 32, 64);
                if (q == 0) {
                    atomicAdd(&denom[col + l16], cp0);
                    atomicAdd(&denom[col + 16 + l16], cp1);
                }
            }
        };

        // double-buffered sweep over units [u, uend) of this row-tile
        int ur        = u - srt;
        const int urn = uend - srt;
        loadB(bufA, rt * 256 + ur * 32);
        while (ur + 2 <= urn) {
            loadB(bufB, rt * 256 + (ur + 1) * 32);
            compute(bufA, ur);
            int nx = ur + 2;
            if (nx >= urn) nx = urn - 1;     // clamp: preloads odd tail unit
            loadB(bufA, rt * 256 + nx * 32);
            compute(bufB, ur + 1);
            ur += 2;
        }
        if (ur < urn) compute(bufA, ur);     // odd tail (bufA holds its cols)

        // row-sum flush: reduce across the 16 lanes holding the same row
        #pragma unroll
        for (int mt = 0; mt < 4; ++mt)
            #pragma unroll
            for (int r = 0; r < 4; ++r) {
                float s = rowsum[mt][r];
                s += __shfl_xor(s, 1, 64);
                s += __shfl_xor(s, 2, 64);
                s += __shfl_xor(s, 4, 64);
                s += __shfl_xor(s, 8, 64);
                rowsum[mt][r] = s;
            }
        if (l16 == 0) {
            #pragma unroll
            for (int mt = 0; mt < 4; ++mt)
                #pragma unroll
                for (int r = 0; r < 4; ++r)
                    atomicAdd(&denom[rowb + mt * 16 + q * 4 + r], rowsum[mt][r]);
        }

        u = uend;
        if (u < u1) { ++rt; snext += 256 - 8 * rt; }
    }
}

__global__ __launch_bounds__(1024) void k_finish(
    const float* __restrict__ denom, const float* __restrict__ pos,
    float* __restrict__ out)
{
    __shared__ float red[16];
    const int t = threadIdx.x;
    const int lane = t & 63, wv = t >> 6;
    float s = 0.0f;
    for (int i = t; i < NROWS; i += 1024) s += __logf(denom[i]);
    float p = 0.0f;
    for (int i = t; i < N_PAIRS; i += 1024) p += pos[i];
    float v = s - 4.0f * p;   // sum_i pos_i/T over 2N rows = 4 * sum_p cos_p
    #pragma unroll
    for (int off = 1; off < 64; off <<= 1) v += __shfl_xor(v, off, 64);
    if (lane == 0) red[wv] = v;
    __syncthreads();
    if (wv == 0) {
        float x = (lane < 16) ? red[lane] : 0.0f;
        #pragma unroll
        for (int off = 1; off < 16; off <<= 1) x += __shfl_xor(x, off, 64);
        if (lane == 0) out[0] = x / (float)NROWS;
    }
}

extern "C" void kernel_launch(void* const* d_in, const int* in_sizes, int n_in,
                              void* d_out, int out_size, void* d_ws, size_t ws_size,
                              hipStream_t stream) {
    const float* z1 = (const float*)d_in[0];
    const float* z2 = (const float*)d_in[1];
    float* out = (float*)d_out;

    char* ws = (char*)d_ws;
    __hip_bfloat16* pack = (__hip_bfloat16*)ws;                // 2 MB
    float* denom = (float*)(ws + (size_t)NROWS * ZDIM * 2);    // 32 KB
    float* pos   = denom + NROWS;                              // 16 KB

    k_normalize<<<N_PAIRS / 4, 256, 0, stream>>>(z1, z2, pack, pos, denom);
    k_simsum<<<GRID_SIM, 256, 0, stream>>>(pack, denom);
    k_finish<<<1, 1024, 0, stream>>>(denom, pos, out);
}

// Round 7
// 82.260 us; speedup vs baseline: 2.0342x; 1.0861x over previous
//
#include <hip/hip_runtime.h>
#include <hip/hip_bf16.h>

// NT-Xent loss, N=4096, Z=128, T=0.5.
//
// FINAL (restored round-1 config -- best measured: 82.1 us).
//
// Session findings (MI355X, gfx950):
// - Timed window = 42us harness poison-fill (untouchable, 80% HBM) +
//   ~16-23us dispatch-boundary machinery + ~15-18us of kernels.
// - Triangle symmetry (row path + mirrored col path over 4224 32-col units,
//   strip-partitioned over exactly 512 blocks) halved MFMA/exp2/frag traffic:
//   +3.5us win. Work reduction helps; overlap tricks don't (clock-ramp-bound:
//   tiny kernels after a memory-saturating fill never reach max clock).
// - Grid 1024 (16 waves/CU) REGRESSED (+7us): not wave-starved; extra
//   A-panel reloads + flush atomics cost more than TLP gains.
// - cg::grid.sync REGRESSED (+85us): per-block agent fences (whole-L2
//   wb/inv x512) + s_sleep backoff. Never grid.sync on gfx950.
// - Per-block __threadfence ticket REGRESSED (+48us): same L2-walk cost.
// - Fence-free ticket (vmcnt-drain + relaxed-atomic reads) correct but
//   still lost 8us vs a plain k_finish dispatch. Tickets lose, period.
// - exp2 trans-pipe (~7us busy) is the largest in-kernel pipe; its count is
//   matrix-size-bound and irreducible. MFMA ~3.8us, VALU ~5us, L2 ~2us.
//
//  k_normalize: row-normalize (fp32), quantize bf16 scaled by
//               QS = sqrt(2*log2(e)) (folds 1/T=2 and exp->exp2), write in
//               fragment order; exact fp32 pair-cosines pos[4096]; zero denom.
//  k_simsum:    denom[i] = sum_{j!=i} exp(2*sim_ij), triangle + mirror.
//  k_finish:    out = (sum_i log denom_i - 4 * sum_p pos_p) / 8192

#define N_PAIRS 4096
#define ZDIM    128
#define NROWS   8192
#define QS 1.6986437717f   // sqrt(2 * log2(e))
#define GRID_SIM 512

typedef __bf16 bf16x8 __attribute__((ext_vector_type(8)));
typedef float  floatx4 __attribute__((ext_vector_type(4)));

__global__ __launch_bounds__(256) void k_normalize(
    const float* __restrict__ z1, const float* __restrict__ z2,
    __hip_bfloat16* __restrict__ pack, float* __restrict__ pos,
    float* __restrict__ denom)
{
    const int zi = blockIdx.x * 256 + threadIdx.x;   // grid 1024 blocks
    if (zi < NROWS) denom[zi] = 0.0f;

    const int w = threadIdx.x >> 6;
    const int lane = threadIdx.x & 63;
    const int p = blockIdx.x * 4 + w;            // pair index, < 4096
    const float2 a = ((const float2*)(z1 + (size_t)p * ZDIM))[lane];
    const float2 b = ((const float2*)(z2 + (size_t)p * ZDIM))[lane];
    float s1 = a.x * a.x + a.y * a.y;
    float s2 = b.x * b.x + b.y * b.y;
    float d  = a.x * b.x + a.y * b.y;
    #pragma unroll
    for (int off = 1; off < 64; off <<= 1) {
        s1 += __shfl_xor(s1, off, 64);
        s2 += __shfl_xor(s2, off, 64);
        d  += __shfl_xor(d,  off, 64);
    }
    const float n1 = fmaxf(sqrtf(s1), 1e-8f);
    const float n2 = fmaxf(sqrtf(s2), 1e-8f);
    const float i1 = 1.0f / n1, i2 = 1.0f / n2;
    const float q1 = i1 * QS, q2 = i2 * QS;
    float2 na; na.x = a.x * q1; na.y = a.y * q1;
    float2 nb; nb.x = b.x * q2; nb.y = b.y * q2;

    // lane holds elements e0=2*lane, e0+1 of its row:
    //   ks = lane>>4 ; q = (lane>>2)&3 ; j = (lane&3)*2
    // pack elem idx for row r: ((r>>4)*4 + ks)*512 + q*128 + (r&15)*8 + j
    const int ks = lane >> 4;
    const int qq = (lane >> 2) & 3;
    const int jj = (lane & 3) * 2;
    const int r1 = p, r2 = p + N_PAIRS;
    const size_t i1e = ((size_t)((r1 >> 4) * 4 + ks)) * 512 + qq * 128 + (r1 & 15) * 8 + jj;
    const size_t i2e = ((size_t)((r2 >> 4) * 4 + ks)) * 512 + qq * 128 + (r2 & 15) * 8 + jj;
    *(__hip_bfloat162*)(pack + i1e) = __float22bfloat162_rn(na);
    *(__hip_bfloat162*)(pack + i2e) = __float22bfloat162_rn(nb);
    if (lane == 0) pos[p] = d * i1 * i2;
}

// Upper-triangle strip schedule.
// Unit = 256 rows (one row-tile rt) x 32 cols. Row rt contributes units
// ur = 0..(255-8*rt); col = rt*256 + ur*32. Units ur<8 are the diagonal
// 256x256 band: row-only accumulation + self-mask (both orderings of a
// within-band pair occur inside the band). Units ur>=8 are strictly upper:
// accumulate row path AND mirrored col path.
// Global unit count: sum_rt (256-8*rt) = 4224 = 512 blocks * 8.25.
// Block b handles units [33b/4, 33(b+1)/4) -- 8 or 9 units, contiguous,
// crossing a row-tile boundary (A-frag reload) in only ~31 blocks.
__global__ __launch_bounds__(256) void k_simsum(
    const __hip_bfloat16* __restrict__ pack, float* __restrict__ denom)
{
    const int tid  = threadIdx.x;
    const int lane = tid & 63;
    const int w    = tid >> 6;
    const int q    = lane >> 4;         // quad 0..3
    const int l16  = lane & 15;

    const int b  = blockIdx.x;
    int u        = (33 * b) >> 2;       // first global unit
    const int u1 = (33 * b + 33) >> 2;  // one past last

    // S(rt) = 256*rt - 4*rt*(rt-1); find rt with S(rt) <= u < S(rt+1)
    int rt = 0, snext = 256;            // snext = S(rt+1)
    while (u >= snext) { ++rt; snext += 256 - 8 * rt; }

    bf16x8 bufA[4][2], bufB[4][2];

    auto loadB = [&](bf16x8 (&buf)[4][2], int col) {
        const __hip_bfloat16* bp = pack + (size_t)col * 128 + lane * 8;
        #pragma unroll
        for (int ks = 0; ks < 4; ++ks)      // ks-major: first MFMA waits least
            #pragma unroll
            for (int nt = 0; nt < 2; ++nt)
                buf[ks][nt] = *(const bf16x8*)(bp + nt * 2048 + ks * 512);
    };

    while (u < u1) {                    // per row-tile segment (1-2 iterations)
        const int srt  = snext - (256 - 8 * rt);   // S(rt)
        const int uend = (u1 < snext) ? u1 : snext;
        const int rowb = rt * 256 + w * 64;

        // persistent A fragments: wave's 64 rows x full K=128 (64 VGPRs)
        const __hip_bfloat16* Abase = pack + (size_t)rowb * 128 + lane * 8;
        bf16x8 afrag[4][4];              // [mt][ks]
        #pragma unroll
        for (int mt = 0; mt < 4; ++mt)
            #pragma unroll
            for (int ks = 0; ks < 4; ++ks)
                afrag[mt][ks] = *(const bf16x8*)(Abase + mt * 2048 + ks * 512);

        float rowsum[4][4];              // [mt][r]
        #pragma unroll
        for (int mt = 0; mt < 4; ++mt)
            #pragma unroll
            for (int r = 0; r < 4; ++r) rowsum[mt][r] = 0.0f;

        auto compute = [&](bf16x8 (&buf)[4][2], int ur) {
            const int  col  = rt * 256 + ur * 32;
            const bool band = (ur < 8);            // wave-uniform
            floatx4 acc[4][2];
            #pragma unroll
            for (int mt = 0; mt < 4; ++mt)
                #pragma unroll
                for (int nt = 0; nt < 2; ++nt) {
                    acc[mt][nt].x = 0.f; acc[mt][nt].y = 0.f;
                    acc[mt][nt].z = 0.f; acc[mt][nt].w = 0.f;
                }
            #pragma unroll
            for (int ks = 0; ks < 4; ++ks)
                #pragma unroll
                for (int mt = 0; mt < 4; ++mt)
                    #pragma unroll
                    for (int nt = 0; nt < 2; ++nt)
                        acc[mt][nt] = __builtin_amdgcn_mfma_f32_16x16x32_bf16(
                            afrag[mt][ks], buf[ks][nt], acc[mt][nt], 0, 0, 0);
            // fused epilogue. C/D layout: col = l16, row = q*4 + r (m89/m91).
            float cp0 = 0.0f, cp1 = 0.0f;   // col-path partials per nt tile
            #pragma unroll
            for (int mt = 0; mt < 4; ++mt) {
                const int rowtb = rowb + mt * 16;
                #pragma unroll
                for (int nt = 0; nt < 2; ++nt) {
                    const int coltb = col + nt * 16;
                    if (band && rowtb == coltb) {   // wave-uniform: diag tile
                        #pragma unroll
                        for (int r = 0; r < 4; ++r) {
                            const float e = __builtin_amdgcn_exp2f(acc[mt][nt][r]);
                            rowsum[mt][r] += (l16 == q * 4 + r) ? 0.0f : e;
                        }
                    } else {
                        #pragma unroll
                        for (int r = 0; r < 4; ++r) {
                            const float e = __builtin_amdgcn_exp2f(acc[mt][nt][r]);
                            rowsum[mt][r] += e;
                            if (!band) { if (nt == 0) cp0 += e; else cp1 += e; }
                        }
                    }
                }
            }
            if (!band) {
                // col path: reduce across q -> all 64 wave rows, then mirror
                cp0 += __shfl_xor(cp0, 16, 64);
                cp0 += __shfl_xor(cp0, 32, 64);
                cp1 += __shfl_xor(cp1, 16, 64);
                cp1 += __shfl_xor(cp1, 32, 64);
                if (q == 0) {
                    atomicAdd(&denom[col + l16], cp0);
                    atomicAdd(&denom[col + 16 + l16], cp1);
                }
            }
        };

        // double-buffered sweep over units [u, uend) of this row-tile
        int ur        = u - srt;
        const int urn = uend - srt;
        loadB(bufA, rt * 256 + ur * 32);
        while (ur + 2 <= urn) {
            loadB(bufB, rt * 256 + (ur + 1) * 32);
            compute(bufA, ur);
            int nx = ur + 2;
            if (nx >= urn) nx = urn - 1;     // clamp: preloads odd tail unit
            loadB(bufA, rt * 256 + nx * 32);
            compute(bufB, ur + 1);
            ur += 2;
        }
        if (ur < urn) compute(bufA, ur);     // odd tail (bufA holds its cols)

        // row-sum flush: reduce across the 16 lanes holding the same row
        #pragma unroll
        for (int mt = 0; mt < 4; ++mt)
            #pragma unroll
            for (int r = 0; r < 4; ++r) {
                float s = rowsum[mt][r];
                s += __shfl_xor(s, 1, 64);
                s += __shfl_xor(s, 2, 64);
                s += __shfl_xor(s, 4, 64);
                s += __shfl_xor(s, 8, 64);
                rowsum[mt][r] = s;
            }
        if (l16 == 0) {
            #pragma unroll
            for (int mt = 0; mt < 4; ++mt)
                #pragma unroll
                for (int r = 0; r < 4; ++r)
                    atomicAdd(&denom[rowb + mt * 16 + q * 4 + r], rowsum[mt][r]);
        }

        u = uend;
        if (u < u1) { ++rt; snext += 256 - 8 * rt; }
    }
}

__global__ __launch_bounds__(1024) void k_finish(
    const float* __restrict__ denom, const float* __restrict__ pos,
    float* __restrict__ out)
{
    __shared__ float red[16];
    const int t = threadIdx.x;
    const int lane = t & 63, wv = t >> 6;
    float s = 0.0f;
    for (int i = t; i < NROWS; i += 1024) s += __logf(denom[i]);
    float p = 0.0f;
    for (int i = t; i < N_PAIRS; i += 1024) p += pos[i];
    float v = s - 4.0f * p;   // sum_i pos_i/T over 2N rows = 4 * sum_p cos_p
    #pragma unroll
    for (int off = 1; off < 64; off <<= 1) v += __shfl_xor(v, off, 64);
    if (lane == 0) red[wv] = v;
    __syncthreads();
    if (wv == 0) {
        float x = (lane < 16) ? red[lane] : 0.0f;
        #pragma unroll
        for (int off = 1; off < 16; off <<= 1) x += __shfl_xor(x, off, 64);
        if (lane == 0) out[0] = x / (float)NROWS;
    }
}

extern "C" void kernel_launch(void* const* d_in, const int* in_sizes, int n_in,
                              void* d_out, int out_size, void* d_ws, size_t ws_size,
                              hipStream_t stream) {
    const float* z1 = (const float*)d_in[0];
    const float* z2 = (const float*)d_in[1];
    float* out = (float*)d_out;

    char* ws = (char*)d_ws;
    __hip_bfloat16* pack = (__hip_bfloat16*)ws;                // 2 MB
    float* denom = (float*)(ws + (size_t)NROWS * ZDIM * 2);    // 32 KB
    float* pos   = denom + NROWS;                              // 16 KB

    k_normalize<<<N_PAIRS / 4, 256, 0, stream>>>(z1, z2, pack, pos, denom);
    k_simsum<<<GRID_SIM, 256, 0, stream>>>(pack, denom);
    k_finish<<<1, 1024, 0, stream>>>(denom, pos, out);
}